// Round 3
// baseline (397.718 us; speedup 1.0000x reference)
//
#include <hip/hip_runtime.h>
#include <math.h>

#define LM 512
#define TLEN 1024
#define TINY_F 1.17549435e-38f

// ---------------------------------------------------------------------------
// DPP helpers (validated in round 2: pure-VALU lane moves).
// ctrl: row_shr:N = 0x110|N, wave_shr:1 = 0x138, row_bcast:15 = 0x142,
//       row_bcast:31 = 0x143
// ---------------------------------------------------------------------------
template<int Ctrl, int RowMask>
__device__ __forceinline__ float fdpp(float oldv, float src) {
    int r = __builtin_amdgcn_update_dpp(
        __builtin_bit_cast(int, oldv), __builtin_bit_cast(int, src),
        Ctrl, RowMask, 0xF, false);
    return __builtin_bit_cast(float, r);
}

__device__ __forceinline__ float rdlane(float v, int lane) {
    return __builtin_bit_cast(float,
        __builtin_amdgcn_readlane(__builtin_bit_cast(int, v), lane));
}

// inclusive prefix-sum across 64 lanes (std GCN idiom); lane63 = total
__device__ __forceinline__ float wave_incl_scan(float v) {
    v += fdpp<0x111, 0xF>(0.f, v);
    v += fdpp<0x112, 0xF>(0.f, v);
    v += fdpp<0x114, 0xF>(0.f, v);
    v += fdpp<0x118, 0xF>(0.f, v);
    v += fdpp<0x142, 0xA>(0.f, v);
    v += fdpp<0x143, 0xC>(0.f, v);
    return v;
}

// ---------------------------------------------------------------------------
// Single fused kernel: per-block prologue rebuilds all HMM parameters from
// raw inputs (redundantly per block, ~us, parallel across 128 CUs), then the
// 1023-step forward recurrence. One wave (64 lanes) per batch element,
// 8 match + 8 insert states per lane.
// ---------------------------------------------------------------------------
__global__ __launch_bounds__(64, 1) void hmm_forward(
    const int* __restrict__ seq,
    const float* __restrict__ em,   const float* __restrict__ ins,
    const float* __restrict__ flank,const float* __restrict__ btm,
    const float* __restrict__ m2e,  const float* __restrict__ mtm,
    const float* __restrict__ m2i,  const float* __restrict__ i2m,
    const float* __restrict__ i2i,  const float* __restrict__ mtd,
    const float* __restrict__ dtm,  const float* __restrict__ dtd,
    const float* __restrict__ lfl,  const float* __restrict__ lfe,
    const float* __restrict__ e2u,  const float* __restrict__ e2r,
    const float* __restrict__ e2t,
    float* __restrict__ out)
{
    __shared__ __align__(16) float sEmb[25 * 512];   // interleaved emission
    __shared__ __align__(16) int   sSeq[TLEN];
    __shared__ float sIns[32];
    __shared__ float sIncl[512];    // inclusive sum of log(dtdp)
    __shared__ float sMtmp[512], sI2mp[512], sDtmp[512], sDtdp[512], sMtdm[512];

    const int lane = threadIdx.x;
    const int b = blockIdx.x;

    // ---- stage sequence ----
    {
        const int4* s4 = (const int4*)(seq + b * TLEN);
        int4* d4 = (int4*)sSeq;
#pragma unroll
        for (int k = lane; k < 256; k += 64) d4[k] = s4[k];
    }

    // =========================== PROLOGUE ==================================
    // position j = 8*lane + e  (match state j <-> ref match index j+1)
    float beginp[8], m2ep_o[8], m2ip_o[8], i2ip_o[8], mtdm_o[8], incl_o[8];
    float mtdp0, inclTot;
    {
        // raw loads + per-row softmaxes
        float dtdp_o[8];
#pragma unroll
        for (int e = 0; e < 8; ++e) {
            int j = lane * 8 + e;
            int idx = j < 511 ? j : 510;
            float mtmv = mtm[idx], m2iv = m2i[idx], m2ev = m2e[idx];
            float mtd1 = mtd[(j + 1) < 512 ? (j + 1) : 511];
            float i2mv = i2m[idx], i2iv = i2i[idx];
            float dtmv = dtm[idx], dtdv = dtd[idx];
            bool v = (j < 511);

            float ea = expf(mtmv), eb = expf(m2iv), ec = expf(m2ev), ed = expf(mtd1);
            float s4v = ea + eb + ec + ed;
            float mtmp_ = v ? ea / s4v : 0.f;
            m2ip_o[e]  = v ? eb / s4v : 0.f;
            m2ep_o[e]  = v ? ec / s4v : 0.f;
            mtdm_o[e]  = v ? ed / s4v : 0.f;   // = mtdp[j+1]

            float ia = expf(i2mv), ib = expf(i2iv);
            float i2mp_ = v ? ia / (ia + ib) : 0.f;
            i2ip_o[e]   = v ? ib / (ia + ib) : 0.f;

            float da = expf(dtmv), db = expf(dtdv);
            float dtmp_ = v ? da / (da + db) : 1.0f;  // dtmp[511] = 1
            dtdp_o[e]   = v ? db / (da + db) : 1.0f;

            sMtmp[j] = mtmp_;
            sI2mp[j] = i2mp_;
            sDtmp[j] = dtmp_;
            sDtdp[j] = dtdp_o[e];
            sMtdm[j] = mtdm_o[e];
        }

        // begin softmax over concat(btm[512], mtd[0])
        float eb8[8], psum = 0.f;
#pragma unroll
        for (int e = 0; e < 8; ++e) { eb8[e] = expf(btm[lane * 8 + e]); psum += eb8[e]; }
        float tot512 = rdlane(wave_incl_scan(psum), 63);
        float emtd0 = expf(mtd[0]);
        float invTot = 1.0f / (tot512 + emtd0);
#pragma unroll
        for (int e = 0; e < 8; ++e) beginp[e] = eb8[e] * invTot;
        mtdp0 = emtd0 * invTot;

        // cplog prefix: incl[j] = sum_{i<=j} log(dtdp[i])  (lw[511]=0)
        float linc[8];
        float lw0 = (lane * 8 + 0 < 511) ? logf(dtdp_o[0]) : 0.f;
        linc[0] = lw0;
#pragma unroll
        for (int e = 1; e < 8; ++e) {
            float lw = (lane * 8 + e < 511) ? logf(dtdp_o[e]) : 0.f;
            linc[e] = linc[e - 1] + lw;
        }
        float laneTot = linc[7];
        float ps = wave_incl_scan(laneTot);
        float laneExcl = ps - laneTot;
        inclTot = rdlane(ps, 63);
#pragma unroll
        for (int e = 0; e < 8; ++e) {
            incl_o[e] = laneExcl + linc[e];
            sIncl[lane * 8 + e] = incl_o[e];
        }

        // insert-emission softmax (no max-sub, matches rounds 1-2)
        if (lane < 25) {
            float sm = 0.f;
            for (int s = 0; s < 25; ++s) sm += expf(ins[s]);
            sIns[lane] = expf(ins[lane]) / sm;
        }

        // match emission softmax -> interleaved LDS table
#pragma unroll 1
        for (int e = 0; e < 8; ++e) {
            int j = lane * 8 + e;
            const float* row = em + j * 25;
            float r[25];
#pragma unroll
            for (int s = 0; s < 25; ++s) r[s] = row[s];
            float mx = r[0];
#pragma unroll
            for (int s = 1; s < 25; ++s) mx = fmaxf(mx, r[s]);
            float sm = 0.f;
#pragma unroll
            for (int s = 0; s < 25; ++s) { r[s] = expf(r[s] - mx); sm += r[s]; }
            float inv = 1.0f / sm;
            int pos = ((e >> 2) << 8) | (lane << 2) | (e & 3);
#pragma unroll
            for (int s = 0; s < 25; ++s) sEmb[s * 512 + pos] = r[s] * inv;
        }
    }

    // scalar transition params (all lanes redundantly)
    float floop, fexit, p0, c1ep0, c1ep1, ep0, ep1, U0, RF0, omp0;
    {
        float fl = expf(lfl[0]), fe = expf(lfe[0]); float fs = fl + fe;
        floop = fl / fs; fexit = fe / fs;
        float eu = expf(e2u[0]), er = expf(e2r[0]), et = expf(e2t[0]);
        float es = eu + er + et; ep0 = eu / es; ep1 = er / es;
        p0 = 1.0f / (1.0f + expf(-flank[0]));
        float be = mtdp0 * expf(inclTot);  // * dtmp[511]=1 ; underflows to 0 like ref
        c1ep0 = fexit * be * ep0;
        c1ep1 = fexit * be * ep1;
        U0  = (1.0f - p0) * be * ep0;
        RF0 = (1.0f - p0) * be * ep1;
        omp0 = 1.0f - p0;
    }

    // per-lane coefficient arrays (reads of [j-1] via LDS scratch)
    float enter_[8], mtm_[8], i2m_[8], dtm_[8], dtmM_[8], wC_[8], mC_[8];
    float m2i_[8], i2i_[8], m2e_[8];
#pragma unroll
    for (int e = 0; e < 8; ++e) {
        int j = lane * 8 + e;
        bool g = (j >= 1);
        mtm_[e] = g ? sMtmp[j - 1] : 0.f;
        i2m_[e] = g ? sI2mp[j - 1] : 0.f;
        dtm_[e] = g ? sDtmp[j - 1] : 0.f;
        mC_[e]  = g ? sDtdp[j - 1] : 0.f;
        wC_[e]  = g ? sMtdm[j - 1] : 0.f;     // = mtdp[j]
        float cpjm1 = (j >= 2) ? sIncl[j - 2] : 0.f;  // cplog[j-1]
        enter_[e] = g ? beginp[e] + mtdp0 * expf(cpjm1) * dtm_[e] : beginp[e];
        m2i_[e] = m2ip_o[e];
        i2i_[e] = i2ip_o[e];
        m2e_[e] = (j < 511)
            ? m2ep_o[e] + mtdm_o[e] * expf(inclTot - incl_o[e])
            : 1.0f;
    }

    // derived constants: local M-prefix, Qp fold, Sklansky stage consts
    float dtmM0 = dtm_[0];
    {
        float Mp = mC_[0];
        dtmM_[0] = dtm_[0];
#pragma unroll
        for (int e = 1; e < 8; ++e) { dtmM_[e] = dtm_[e] * Mp; Mp *= mC_[e]; }
    }
    float Mpre7;
    {
        float Mp = mC_[0];
#pragma unroll
        for (int e = 1; e < 8; ++e) Mp *= mC_[e];
        Mpre7 = Mp;
    }
    const float K23 = mC_[2] * mC_[3];
    const float K67 = mC_[6] * mC_[7];
    const float K34 = mC_[4];
    const float K35 = K34 * mC_[5];
    const float K36 = K35 * mC_[6];
    const float K37 = K36 * mC_[7];

    // wave-scan stage multipliers (constant; validated round 2)
    float MsK0, MsK1, MsK2, MsK3, MsK4, MsK5;
    {
        float Ms = Mpre7, Mo;
        Mo = fdpp<0x111, 0xF>(1.f, Ms); MsK0 = Ms; Ms *= Mo;
        Mo = fdpp<0x112, 0xF>(1.f, Ms); MsK1 = Ms; Ms *= Mo;
        Mo = fdpp<0x114, 0xF>(1.f, Ms); MsK2 = Ms; Ms *= Mo;
        Mo = fdpp<0x118, 0xF>(1.f, Ms); MsK3 = Ms; Ms *= Mo;
        Mo = fdpp<0x142, 0xA>(1.f, Ms); MsK4 = Ms; Ms *= Mo;
        Mo = fdpp<0x143, 0xC>(1.f, Ms); MsK5 = Ms; Ms *= Mo;
    }

    // =========================== MAIN LOOP =================================
    float EmA[8], EmB[8], EiA, EiB;
    int sym0 = sSeq[0];
    {
        const float4* c4 = (const float4*)(sEmb + (sym0 << 9) + (lane << 2));
        float4 xx = c4[0], yy = c4[64];
        EmA[0] = xx.x; EmA[1] = xx.y; EmA[2] = xx.z; EmA[3] = xx.w;
        EmA[4] = yy.x; EmA[5] = yy.y; EmA[6] = yy.z; EmA[7] = yy.w;
        EiA = sIns[sym0];
    }
    float am[8], ai[8];
#pragma unroll
    for (int e = 0; e < 8; ++e) { am[e] = EmA[e] * (omp0 * enter_[e]); ai[e] = 0.f; }
    float f0 = p0 * EiA;
    float U  = U0 * EiA;
    float RF = RF0 * EiA;
    float ll2 = 0.f;

    int symN = sSeq[1];
    {
        const float4* c4 = (const float4*)(sEmb + (symN << 9) + (lane << 2));
        float4 xx = c4[0], yy = c4[64];
        EmA[0] = xx.x; EmA[1] = xx.y; EmA[2] = xx.z; EmA[3] = xx.w;
        EmA[4] = yy.x; EmA[5] = yy.y; EmA[6] = yy.z; EmA[7] = yy.w;
        EiA = sIns[symN];
    }
    symN = sSeq[2];

#define STEP(T, EmC, EiC, EmN, EiN)                                            \
  {                                                                            \
    { /* prefetch E_{T+1}; fetch s[T+2] */                                     \
      const float4* c4 = (const float4*)(sEmb + (symN << 9) + (lane << 2));    \
      float4 xx = c4[0], yy = c4[64];                                          \
      EmN[0] = xx.x; EmN[1] = xx.y; EmN[2] = xx.z; EmN[3] = xx.w;              \
      EmN[4] = yy.x; EmN[5] = yy.y; EmN[6] = yy.z; EmN[7] = yy.w;              \
      EiN = sIns[symN];                                                        \
      int tn = (T) + 2; tn = tn > TLEN - 1 ? TLEN - 1 : tn;                    \
      symN = sSeq[tn];                                                         \
    }                                                                          \
    float amL = fdpp<0x138, 0xF>(0.f, am[7]);                                  \
    float aiL = fdpp<0x138, 0xF>(0.f, ai[7]);                                  \
    /* local affine prefix, Sklansky depth-3 with constant multipliers */      \
    float A0 = amL * wC_[0];                                                   \
    float A1 = am[0] * wC_[1], A2 = am[1] * wC_[2], A3 = am[2] * wC_[3];       \
    float A4 = am[3] * wC_[4], A5 = am[4] * wC_[5], A6 = am[5] * wC_[6];       \
    float A7 = am[6] * wC_[7];                                                 \
    A1 = fmaf(mC_[1], A0, A1); A3 = fmaf(mC_[3], A2, A3);                      \
    A5 = fmaf(mC_[5], A4, A5); A7 = fmaf(mC_[7], A6, A7);                      \
    A2 = fmaf(mC_[2], A1, A2); A3 = fmaf(K23, A1, A3);                         \
    A6 = fmaf(mC_[6], A5, A6); A7 = fmaf(K67, A5, A7);                         \
    A4 = fmaf(K34, A3, A4); A5 = fmaf(K35, A3, A5);                            \
    A6 = fmaf(K36, A3, A6); A7 = fmaf(K37, A3, A7);                            \
    /* cross-lane affine scan (6 DPP stages, constant MsK) */                  \
    float As = A7;                                                             \
    As = fmaf(MsK0, fdpp<0x111, 0xF>(0.f, As), As);                            \
    As = fmaf(MsK1, fdpp<0x112, 0xF>(0.f, As), As);                            \
    As = fmaf(MsK2, fdpp<0x114, 0xF>(0.f, As), As);                            \
    As = fmaf(MsK3, fdpp<0x118, 0xF>(0.f, As), As);                            \
    As = fmaf(MsK4, fdpp<0x142, 0xA>(0.f, As), As);                            \
    As = fmaf(MsK5, fdpp<0x143, 0xC>(0.f, As), As);                            \
    float carry = fdpp<0x138, 0xF>(0.f, As);                                   \
    /* dsum: two independent depth-4 chains */                                 \
    float d0 = am[0] * m2e_[0];                                                \
    d0 = fmaf(am[1], m2e_[1], d0); d0 = fmaf(am[2], m2e_[2], d0);              \
    d0 = fmaf(am[3], m2e_[3], d0);                                             \
    float d1 = am[4] * m2e_[4];                                                \
    d1 = fmaf(am[5], m2e_[5], d1); d1 = fmaf(am[6], m2e_[6], d1);              \
    d1 = fmaf(am[7], m2e_[7], d1);                                             \
    float dsum = rdlane(wave_incl_scan(d0 + d1), 63);                          \
    /* scalar states */                                                        \
    float aFU = (f0 + U) * fexit;                                              \
    float nf0 = EiC * (f0 * floop);                                            \
    float nU  = EiC * (fmaf(f0, c1ep0, U * (floop + c1ep0)) + dsum * ep0);     \
    float nRF = EiC * ((f0 + U) * c1ep1 + dsum * ep1 + RF * floop);            \
    f0 = nf0; U = nU; RF = nRF;                                                \
    /* fused insert+match update; carry enters 2 ops from am[e] */             \
    _Pragma("unroll")                                                          \
    for (int e = 7; e >= 1; --e) {                                             \
      float iin = ai[e - 1] * i2m_[e];                                         \
      ai[e] = EiC * fmaf(am[e], m2i_[e], ai[e] * i2i_[e]);                     \
      float Ax = (e == 1) ? A0 : (e == 2) ? A1 : (e == 3) ? A2 :               \
                 (e == 4) ? A3 : (e == 5) ? A4 : (e == 6) ? A5 : A6;           \
      float t = fmaf(am[e - 1], mtm_[e], iin);                                 \
      t = fmaf(aFU, enter_[e], t);                                             \
      t = fmaf(dtm_[e], Ax, t);                                                \
      t = fmaf(dtmM_[e], carry, t);                                            \
      am[e] = EmC[e] * t;                                                      \
    }                                                                          \
    {                                                                          \
      float iin = aiL * i2m_[0];                                               \
      ai[0] = EiC * fmaf(am[0], m2i_[0], ai[0] * i2i_[0]);                     \
      float t = fmaf(amL, mtm_[0], iin);                                       \
      t = fmaf(aFU, enter_[0], t);                                             \
      t = fmaf(dtmM0, carry, t);                                               \
      am[0] = EmC[0] * t;                                                      \
    }                                                                          \
    /* deferred normalization every 16 steps */                                \
    if (((T) & 15) == 0 || (T) == TLEN - 1) {                                  \
      float sl = (lane == 0) ? (f0 + U + RF) : 0.f;                            \
      _Pragma("unroll")                                                        \
      for (int e = 0; e < 8; ++e) sl += am[e] + ai[e];                         \
      float s = rdlane(wave_incl_scan(sl), 63) + TINY_F;                       \
      ll2 += __log2f(s);                                                       \
      float inv = 1.0f / s;                                                    \
      _Pragma("unroll")                                                        \
      for (int e = 0; e < 8; ++e) { am[e] *= inv; ai[e] *= inv; }              \
      f0 *= inv; U *= inv; RF *= inv;                                          \
    }                                                                          \
  }

    for (int t = 1; t < TLEN - 1; t += 2) {
        STEP(t, EmA, EiA, EmB, EiB);
        STEP(t + 1, EmB, EiB, EmA, EiA);
    }
    STEP(TLEN - 1, EmA, EiA, EmB, EiB);
#undef STEP

    if (lane == 0) out[b] = ll2 * 0.69314718055994530942f;
}

extern "C" void kernel_launch(void* const* d_in, const int* in_sizes, int n_in,
                              void* d_out, int out_size, void* d_ws, size_t ws_size,
                              hipStream_t stream) {
    const int*   seq   = (const int*)d_in[0];
    const float* em    = (const float*)d_in[1];
    const float* ins   = (const float*)d_in[2];
    const float* flank = (const float*)d_in[3];
    const float* btm   = (const float*)d_in[4];
    const float* m2e   = (const float*)d_in[5];
    const float* mtm   = (const float*)d_in[6];
    const float* m2i   = (const float*)d_in[7];
    const float* i2m   = (const float*)d_in[8];
    const float* i2i   = (const float*)d_in[9];
    const float* mtd   = (const float*)d_in[10];
    const float* dtm   = (const float*)d_in[11];
    const float* dtd   = (const float*)d_in[12];
    const float* lfl   = (const float*)d_in[13];
    const float* lfe   = (const float*)d_in[14];
    const float* e2u   = (const float*)d_in[15];
    const float* e2r   = (const float*)d_in[16];
    const float* e2t   = (const float*)d_in[17];
    float* out = (float*)d_out;

    hipLaunchKernelGGL(hmm_forward, dim3(128), dim3(64), 0, stream,
        seq, em, ins, flank, btm, m2e, mtm, m2i, i2m, i2i, mtd, dtm, dtd,
        lfl, lfe, e2u, e2r, e2t, out);
}

// Round 4
// 378.756 us; speedup vs baseline: 1.0501x; 1.0501x over previous
//
#include <hip/hip_runtime.h>
#include <math.h>

#define LM 512
#define TLEN 1024
#define TINY_F 1.17549435e-38f

// d_ws float layout (total 17920 floats = 71680 B)
#define OFF_ENTER 0
#define OFF_MTM   512
#define OFF_I2M   1024
#define OFF_DTM   1536
#define OFF_WC    2048
#define OFF_MC    2560
#define OFF_M2I   3072
#define OFF_I2I   3584
#define OFF_M2E   4096
#define OFF_INS   4608
#define OFF_SC    4640
#define OFF_EMB   5120

typedef float v2f __attribute__((ext_vector_type(2)));
#define PFMA(a, b, c) __builtin_elementwise_fma((a), (b), (c))

// ---------------------------------------------------------------------------
// DPP helpers. ctrl: row_shr:N = 0x110|N, wave_shr:1 = 0x138,
// row_bcast:15 = 0x142, row_bcast:31 = 0x143
// ---------------------------------------------------------------------------
template<int Ctrl, int RowMask>
__device__ __forceinline__ float fdpp(float oldv, float src) {
    int r = __builtin_amdgcn_update_dpp(
        __builtin_bit_cast(int, oldv), __builtin_bit_cast(int, src),
        Ctrl, RowMask, 0xF, false);
    return __builtin_bit_cast(float, r);
}

__device__ __forceinline__ float rdlane63(float v) {
    return __builtin_bit_cast(float,
        __builtin_amdgcn_readlane(__builtin_bit_cast(int, v), 63));
}

// inclusive prefix-sum across 64 lanes; lane63 = total
__device__ __forceinline__ float wave_incl_scan(float v) {
    v += fdpp<0x111, 0xF>(0.f, v);
    v += fdpp<0x112, 0xF>(0.f, v);
    v += fdpp<0x114, 0xF>(0.f, v);
    v += fdpp<0x118, 0xF>(0.f, v);
    v += fdpp<0x142, 0xA>(0.f, v);
    v += fdpp<0x143, 0xC>(0.f, v);
    return v;
}

// ---------------------------------------------------------------------------
// Setup kernel — verbatim round-2 version (verified; ~14us off critical path).
// ---------------------------------------------------------------------------
__global__ __launch_bounds__(512) void hmm_setup(
    const float* __restrict__ em, const float* __restrict__ ins,
    const float* __restrict__ flank, const float* __restrict__ btm,
    const float* __restrict__ m2e, const float* __restrict__ mtm,
    const float* __restrict__ m2i, const float* __restrict__ i2m,
    const float* __restrict__ i2i, const float* __restrict__ mtd,
    const float* __restrict__ dtm, const float* __restrict__ dtd,
    const float* __restrict__ lfl, const float* __restrict__ lfe,
    const float* __restrict__ e2u, const float* __restrict__ e2r,
    const float* __restrict__ e2t, float* __restrict__ P)
{
    __shared__ float beginp[513];
    __shared__ float mtdp[512], dtmp[512], dtdp[512], cplog[512];
    __shared__ float mtmp[512], m2ip[512], m2ep[512], i2mp[512], i2ip[512];
    __shared__ float rbuf[512], rbuf2[512];
    const int j = threadIdx.x;

    float eb = expf(btm[j]);
    rbuf[j] = eb;
    __syncthreads();
    for (int s = 256; s > 0; s >>= 1) {
        if (j < s) rbuf[j] += rbuf[j + s];
        __syncthreads();
    }
    float e512 = expf(mtd[0]);
    float tot = rbuf[0] + e512;
    beginp[j] = eb / tot;
    if (j == 0) { beginp[512] = e512 / tot; mtdp[0] = e512 / tot; }

    if (j < 511) {
        float a = expf(mtm[j]), b = expf(m2i[j]), c = expf(m2e[j]), d = expf(mtd[j + 1]);
        float s = a + b + c + d;
        mtmp[j] = a / s; m2ip[j] = b / s; m2ep[j] = c / s; mtdp[j + 1] = d / s;
        float ia = expf(i2m[j]), ib = expf(i2i[j]); s = ia + ib;
        i2mp[j] = ia / s; i2ip[j] = ib / s;
        float da = expf(dtm[j]), db = expf(dtd[j]); s = da + db;
        dtmp[j] = da / s; dtdp[j] = db / s;
    }
    if (j == 511) dtmp[511] = 1.0f;
    __syncthreads();

    // parallel prefix: cplog[j] = sum_{i<j} log(dtdp[i])
    {
        float lw = (j >= 1) ? logf(dtdp[j - 1]) : 0.f;
        rbuf[j] = lw;
        __syncthreads();
        float* bufs[2] = { rbuf, rbuf2 };
        int cur = 0;
        for (int off = 1; off < 512; off <<= 1) {
            float v = bufs[cur][j];
            if (j >= off) v += bufs[cur][j - off];
            bufs[cur ^ 1][j] = v;
            cur ^= 1;
            __syncthreads();
        }
        cplog[j] = bufs[cur][j];
    }
    __syncthreads();

    if (j == 0) {
        float sm = 0.f;
        for (int s = 0; s < 25; ++s) sm += expf(ins[s]);
        for (int s = 0; s < 25; ++s) P[OFF_INS + s] = expf(ins[s]) / sm;
        float fl = expf(lfl[0]), fe = expf(lfe[0]); float fs = fl + fe;
        float floop = fl / fs, fexit = fe / fs;
        float eu = expf(e2u[0]), er = expf(e2r[0]), et = expf(e2t[0]);
        float es = eu + er + et; float ep0 = eu / es, ep1 = er / es;
        float p0 = 1.0f / (1.0f + expf(-flank[0]));
        float be = mtdp[0] * expf(cplog[511]) * dtmp[511]; // underflows to 0 like ref fp32
        P[OFF_SC + 0] = floop;
        P[OFF_SC + 1] = fexit;
        P[OFF_SC + 2] = p0;
        P[OFF_SC + 3] = fexit * be * ep0;
        P[OFF_SC + 4] = fexit * be * ep1;
        P[OFF_SC + 5] = ep0;
        P[OFF_SC + 6] = ep1;
        P[OFF_SC + 7] = (1.0f - p0) * be * ep0;
        P[OFF_SC + 8] = (1.0f - p0) * be * ep1;
        P[OFF_SC + 9] = 1.0f - p0;
    }
    __syncthreads();

    float en = beginp[j];
    if (j >= 1) en += mtdp[0] * expf(cplog[j - 1]) * dtmp[j - 1];
    P[OFF_ENTER + j] = en;
    P[OFF_MTM + j] = (j >= 1) ? mtmp[j - 1] : 0.f;
    P[OFF_I2M + j] = (j >= 1) ? i2mp[j - 1] : 0.f;
    P[OFF_DTM + j] = (j >= 1) ? dtmp[j - 1] : 0.f;
    P[OFF_WC  + j] = (j >= 1) ? mtdp[j]     : 0.f;
    P[OFF_MC  + j] = (j >= 1) ? dtdp[j - 1] : 0.f;
    P[OFF_M2I + j] = (j < 511) ? m2ip[j] : 0.f;
    P[OFF_I2I + j] = (j < 511) ? i2ip[j] : 0.f;
    P[OFF_M2E + j] = (j < 511)
        ? (m2ep[j] + mtdp[j + 1] * expf(cplog[511] - cplog[j + 1]))
        : 1.0f;

    // interleaved emission table: pos = ((e>>2)<<8)|(lane<<2)|(e&3)
    {
        const float* row = em + j * 25;
        float mx = row[0];
        for (int s = 1; s < 25; ++s) mx = fmaxf(mx, row[s]);
        float sm = 0.f;
        for (int s = 0; s < 25; ++s) sm += expf(row[s] - mx);
        float inv = 1.0f / sm;
        int lanej = j >> 3, e = j & 7;
        int pos = ((e >> 2) << 8) | (lanej << 2) | (e & 3);
        for (int s = 0; s < 25; ++s)
            P[OFF_EMB + s * 512 + pos] = expf(row[s] - mx) * inv;
    }
}

// ---------------------------------------------------------------------------
// Forward: r2 shell (LDS = emission + ins + seq ONLY; 0 bank conflicts) with
// packed-fp32 (v_pk_*_f32) inner updates, Sklansky local scan, dtmM carry
// fold, 5-stage truncated affine wave-scan, norm every 16.
// ---------------------------------------------------------------------------
__global__ __launch_bounds__(64, 1) void hmm_forward(
    const int* __restrict__ seq, const float* __restrict__ P,
    float* __restrict__ out)
{
    __shared__ __align__(16) float sEmb[25 * 512];
    __shared__ float sIns[32];
    __shared__ __align__(16) int sSeq[TLEN];

    const int lane = threadIdx.x;
    const int b = blockIdx.x;
    const int base = lane * 8;

    // ---- stage LDS ----
    {
        const float4* src = (const float4*)(P + OFF_EMB);
        float4* dst = (float4*)sEmb;
#pragma unroll 5
        for (int k = lane; k < 25 * 128; k += 64) dst[k] = src[k];
        if (lane < 32) sIns[lane] = P[OFF_INS + (lane < 25 ? lane : 0)];
        const int4* s4 = (const int4*)(seq + b * TLEN);
        int4* d4 = (int4*)sSeq;
#pragma unroll
        for (int k = lane; k < 256; k += 64) d4[k] = s4[k];
    }

    // ---- per-lane coefficients (scalar load, packed storage) ----
    float enter_[8], mtm_[8], i2m_[8], dtm_[8], wC_[8], mC_[8], m2i_[8], i2i_[8], m2e_[8];
#pragma unroll
    for (int e = 0; e < 8; ++e) {
        enter_[e] = P[OFF_ENTER + base + e];
        mtm_[e]   = P[OFF_MTM + base + e];
        i2m_[e]   = P[OFF_I2M + base + e];
        dtm_[e]   = P[OFF_DTM + base + e];
        wC_[e]    = P[OFF_WC + base + e];
        mC_[e]    = P[OFF_MC + base + e];
        m2i_[e]   = P[OFF_M2I + base + e];
        i2i_[e]   = P[OFF_I2I + base + e];
        m2e_[e]   = P[OFF_M2E + base + e];
    }
    const float floop = P[OFF_SC + 0], fexit = P[OFF_SC + 1], p0 = P[OFF_SC + 2];
    const float c1ep0 = P[OFF_SC + 3], c1ep1 = P[OFF_SC + 4];
    const float ep0 = P[OFF_SC + 5], ep1 = P[OFF_SC + 6];
    const float U0 = P[OFF_SC + 7], RF0 = P[OFF_SC + 8], omp0 = P[OFF_SC + 9];

    // dtmM fold + local multiplier prefix
    float dtmM_[8], Mpre7;
    {
        float Mp = mC_[0];
        dtmM_[0] = dtm_[0];
#pragma unroll
        for (int e = 1; e < 8; ++e) { dtmM_[e] = dtm_[e] * Mp; Mp *= mC_[e]; }
        Mpre7 = Mp;
    }
    const float K23 = mC_[2] * mC_[3];
    const float K67 = mC_[6] * mC_[7];
    const float K34 = mC_[4];
    const float K35 = K34 * mC_[5];
    const float K36 = K35 * mC_[6];
    const float K37 = K36 * mC_[7];

    // truncated-scan stage multipliers (skip row_shr:8; see round-4 analysis:
    // dropped stage's term <= Mpre7^8 ~ 4e-20 relative -> exact at fp32)
    float MsK0, MsK1, MsK2, MsK4, MsK5;
    {
        float Ms = Mpre7, Mo;
        Mo = fdpp<0x111, 0xF>(1.f, Ms); MsK0 = Ms; Ms *= Mo;
        Mo = fdpp<0x112, 0xF>(1.f, Ms); MsK1 = Ms; Ms *= Mo;
        Mo = fdpp<0x114, 0xF>(1.f, Ms); MsK2 = Ms; Ms *= Mo;
        Mo = fdpp<0x142, 0xA>(1.f, Ms); MsK4 = Ms; Ms *= Mo;
        Mo = fdpp<0x143, 0xC>(1.f, Ms); MsK5 = Ms; Ms *= Mo;
    }

    // packed coefficient pairs
    v2f enter2[4], mtm2[4], i2m2[4], m2i2[4], i2i2[4], m2e2[4], wC2[4], dtmM2[4];
#pragma unroll
    for (int p = 0; p < 4; ++p) {
        enter2[p].x = enter_[2*p]; enter2[p].y = enter_[2*p+1];
        mtm2[p].x   = mtm_[2*p];   mtm2[p].y   = mtm_[2*p+1];
        i2m2[p].x   = i2m_[2*p];   i2m2[p].y   = i2m_[2*p+1];
        m2i2[p].x   = m2i_[2*p];   m2i2[p].y   = m2i_[2*p+1];
        i2i2[p].x   = i2i_[2*p];   i2i2[p].y   = i2i_[2*p+1];
        m2e2[p].x   = m2e_[2*p];   m2e2[p].y   = m2e_[2*p+1];
        wC2[p].x    = wC_[2*p];    wC2[p].y    = wC_[2*p+1];
        dtmM2[p].x  = dtmM_[2*p];  dtmM2[p].y  = dtmM_[2*p+1];
    }

    __syncthreads();

    // ---- init at t=0 ----
    v2f EmA2[4], EmB2[4];
    float EiA, EiB;
    int sym0 = sSeq[0];
    {
        const v2f* c2 = (const v2f*)(sEmb + (sym0 << 9) + (lane << 2));
        EmA2[0] = c2[0]; EmA2[1] = c2[1]; EmA2[2] = c2[128]; EmA2[3] = c2[129];
        EiA = sIns[sym0];
    }
    v2f am2[4], ai2[4];
#pragma unroll
    for (int p = 0; p < 4; ++p) {
        am2[p] = EmA2[p] * (v2f){omp0, omp0} * enter2[p];
        ai2[p] = (v2f){0.f, 0.f};
    }
    float f0 = p0 * EiA;
    float U  = U0 * EiA;
    float RF = RF0 * EiA;
    float ll2 = 0.f;

    // prime pipeline
    int symN = sSeq[1];
    {
        const v2f* c2 = (const v2f*)(sEmb + (symN << 9) + (lane << 2));
        EmA2[0] = c2[0]; EmA2[1] = c2[1]; EmA2[2] = c2[128]; EmA2[3] = c2[129];
        EiA = sIns[symN];
    }
    symN = sSeq[2];

#define STEP(T, EmC2, EiC, EmN2, EiN)                                          \
  {                                                                            \
    { /* prefetch E_{T+1}; fetch s[T+2] */                                     \
      const v2f* c2 = (const v2f*)(sEmb + (symN << 9) + (lane << 2));          \
      EmN2[0] = c2[0]; EmN2[1] = c2[1];                                        \
      EmN2[2] = c2[128]; EmN2[3] = c2[129];                                    \
      EiN = sIns[symN];                                                        \
      int tn = (T) + 2; tn = tn > TLEN - 1 ? TLEN - 1 : tn;                    \
      symN = sSeq[tn];                                                         \
    }                                                                          \
    float amL = fdpp<0x138, 0xF>(0.f, am2[3].y);                               \
    float aiL = fdpp<0x138, 0xF>(0.f, ai2[3].y);                               \
    /* shifted pairs {x[e-1], x[e]} */                                         \
    v2f amm1_0, amm1_1, amm1_2, amm1_3, aim1_0, aim1_1, aim1_2, aim1_3;        \
    amm1_0.x = amL;       amm1_0.y = am2[0].x;                                 \
    amm1_1.x = am2[0].y;  amm1_1.y = am2[1].x;                                 \
    amm1_2.x = am2[1].y;  amm1_2.y = am2[2].x;                                 \
    amm1_3.x = am2[2].y;  amm1_3.y = am2[3].x;                                 \
    aim1_0.x = aiL;       aim1_0.y = ai2[0].x;                                 \
    aim1_1.x = ai2[0].y;  aim1_1.y = ai2[1].x;                                 \
    aim1_2.x = ai2[1].y;  aim1_2.y = ai2[2].x;                                 \
    aim1_3.x = ai2[2].y;  aim1_3.y = ai2[3].x;                                 \
    /* local affine prefix: packed muls, Sklansky on components */             \
    v2f Au0 = amm1_0 * wC2[0], Au1 = amm1_1 * wC2[1];                          \
    v2f Au2 = amm1_2 * wC2[2], Au3 = amm1_3 * wC2[3];                          \
    Au0.y = fmaf(mC_[1], Au0.x, Au0.y);                                        \
    Au1.y = fmaf(mC_[3], Au1.x, Au1.y);                                        \
    Au2.y = fmaf(mC_[5], Au2.x, Au2.y);                                        \
    Au3.y = fmaf(mC_[7], Au3.x, Au3.y);                                        \
    Au1.x = fmaf(mC_[2], Au0.y, Au1.x);                                        \
    Au1.y = fmaf(K23,    Au0.y, Au1.y);                                        \
    Au3.x = fmaf(mC_[6], Au2.y, Au3.x);                                        \
    Au3.y = fmaf(K67,    Au2.y, Au3.y);                                        \
    Au2.x = fmaf(K34, Au1.y, Au2.x);                                           \
    Au2.y = fmaf(K35, Au1.y, Au2.y);                                           \
    Au3.x = fmaf(K36, Au1.y, Au3.x);                                           \
    Au3.y = fmaf(K37, Au1.y, Au3.y);                                           \
    /* dsum partial (independent chain, interleaves with wave-scan) */         \
    v2f dv = am2[0] * m2e2[0];                                                 \
    dv = PFMA(am2[1], m2e2[1], dv);                                            \
    dv = PFMA(am2[2], m2e2[2], dv);                                            \
    dv = PFMA(am2[3], m2e2[3], dv);                                            \
    float dl = dv.x + dv.y;                                                    \
    /* truncated affine wave-scan (5 stages) interleaved with dsum scan */     \
    float As = Au3.y;                                                          \
    As = fmaf(MsK0, fdpp<0x111, 0xF>(0.f, As), As);                            \
    dl += fdpp<0x111, 0xF>(0.f, dl);                                           \
    As = fmaf(MsK1, fdpp<0x112, 0xF>(0.f, As), As);                            \
    dl += fdpp<0x112, 0xF>(0.f, dl);                                           \
    As = fmaf(MsK2, fdpp<0x114, 0xF>(0.f, As), As);                            \
    dl += fdpp<0x114, 0xF>(0.f, dl);                                           \
    As = fmaf(MsK4, fdpp<0x142, 0xA>(0.f, As), As);                            \
    dl += fdpp<0x118, 0xF>(0.f, dl);                                           \
    As = fmaf(MsK5, fdpp<0x143, 0xC>(0.f, As), As);                            \
    dl += fdpp<0x142, 0xA>(0.f, dl);                                           \
    float carry = fdpp<0x138, 0xF>(0.f, As);                                   \
    dl += fdpp<0x143, 0xC>(0.f, dl);                                           \
    float dsum = rdlane63(dl);                                                 \
    /* scalar states */                                                        \
    float aFU = (f0 + U) * fexit;                                              \
    float nf0 = EiC * (f0 * floop);                                            \
    float nU  = EiC * (fmaf(f0, c1ep0, U * (floop + c1ep0)) + dsum * ep0);     \
    float nRF = EiC * ((f0 + U) * c1ep1 + dsum * ep1 + RF * floop);            \
    f0 = nf0; U = nU; RF = nRF;                                                \
    /* packed insert update (old am2, old ai2) */                              \
    v2f EiC2 = {EiC, EiC};                                                     \
    ai2[0] = EiC2 * PFMA(am2[0], m2i2[0], ai2[0] * i2i2[0]);                   \
    ai2[1] = EiC2 * PFMA(am2[1], m2i2[1], ai2[1] * i2i2[1]);                   \
    ai2[2] = EiC2 * PFMA(am2[2], m2i2[2], ai2[2] * i2i2[2]);                   \
    ai2[3] = EiC2 * PFMA(am2[3], m2i2[3], ai2[3] * i2i2[3]);                   \
    /* packed match update; scalar A-terms (e>=1), carry 1 fma from am */      \
    v2f aFU2 = {aFU, aFU};                                                     \
    v2f carry2 = {carry, carry};                                               \
    v2f t0 = PFMA(amm1_0, mtm2[0], aim1_0 * i2m2[0]);                          \
    v2f t1 = PFMA(amm1_1, mtm2[1], aim1_1 * i2m2[1]);                          \
    v2f t2 = PFMA(amm1_2, mtm2[2], aim1_2 * i2m2[2]);                          \
    v2f t3 = PFMA(amm1_3, mtm2[3], aim1_3 * i2m2[3]);                          \
    t0 = PFMA(aFU2, enter2[0], t0);                                            \
    t1 = PFMA(aFU2, enter2[1], t1);                                            \
    t2 = PFMA(aFU2, enter2[2], t2);                                            \
    t3 = PFMA(aFU2, enter2[3], t3);                                            \
    t0.y = fmaf(dtm_[1], Au0.x, t0.y);                                         \
    t1.x = fmaf(dtm_[2], Au0.y, t1.x);                                         \
    t1.y = fmaf(dtm_[3], Au1.x, t1.y);                                         \
    t2.x = fmaf(dtm_[4], Au1.y, t2.x);                                         \
    t2.y = fmaf(dtm_[5], Au2.x, t2.y);                                         \
    t3.x = fmaf(dtm_[6], Au2.y, t3.x);                                         \
    t3.y = fmaf(dtm_[7], Au3.x, t3.y);                                         \
    t0 = PFMA(dtmM2[0], carry2, t0);                                           \
    t1 = PFMA(dtmM2[1], carry2, t1);                                           \
    t2 = PFMA(dtmM2[2], carry2, t2);                                           \
    t3 = PFMA(dtmM2[3], carry2, t3);                                           \
    am2[0] = EmC2[0] * t0;                                                     \
    am2[1] = EmC2[1] * t1;                                                     \
    am2[2] = EmC2[2] * t2;                                                     \
    am2[3] = EmC2[3] * t3;                                                     \
    /* deferred normalization every 16 steps */                                \
    if (((T) & 15) == 0 || (T) == TLEN - 1) {                                  \
      v2f ns = am2[0] + ai2[0];                                                \
      ns += am2[1] + ai2[1];                                                   \
      ns += am2[2] + ai2[2];                                                   \
      ns += am2[3] + ai2[3];                                                   \
      float sl = ns.x + ns.y + ((lane == 0) ? (f0 + U + RF) : 0.f);            \
      float s = rdlane63(wave_incl_scan(sl)) + TINY_F;                         \
      ll2 += __log2f(s);                                                       \
      float inv = 1.0f / s;                                                    \
      v2f inv2 = {inv, inv};                                                   \
      am2[0] *= inv2; am2[1] *= inv2; am2[2] *= inv2; am2[3] *= inv2;          \
      ai2[0] *= inv2; ai2[1] *= inv2; ai2[2] *= inv2; ai2[3] *= inv2;          \
      f0 *= inv; U *= inv; RF *= inv;                                          \
    }                                                                          \
  }

    for (int t = 1; t < TLEN - 1; t += 2) {
        STEP(t, EmA2, EiA, EmB2, EiB);
        STEP(t + 1, EmB2, EiB, EmA2, EiA);
    }
    STEP(TLEN - 1, EmA2, EiA, EmB2, EiB);
#undef STEP

    if (lane == 0) out[b] = ll2 * 0.69314718055994530942f;
}

extern "C" void kernel_launch(void* const* d_in, const int* in_sizes, int n_in,
                              void* d_out, int out_size, void* d_ws, size_t ws_size,
                              hipStream_t stream) {
    const int*   seq   = (const int*)d_in[0];
    const float* em    = (const float*)d_in[1];
    const float* ins   = (const float*)d_in[2];
    const float* flank = (const float*)d_in[3];
    const float* btm   = (const float*)d_in[4];
    const float* m2e   = (const float*)d_in[5];
    const float* mtm   = (const float*)d_in[6];
    const float* m2i   = (const float*)d_in[7];
    const float* i2m   = (const float*)d_in[8];
    const float* i2i   = (const float*)d_in[9];
    const float* mtd   = (const float*)d_in[10];
    const float* dtm   = (const float*)d_in[11];
    const float* dtd   = (const float*)d_in[12];
    const float* lfl   = (const float*)d_in[13];
    const float* lfe   = (const float*)d_in[14];
    const float* e2u   = (const float*)d_in[15];
    const float* e2r   = (const float*)d_in[16];
    const float* e2t   = (const float*)d_in[17];
    float* P = (float*)d_ws;  // needs 71680 B
    float* out = (float*)d_out;

    hipLaunchKernelGGL(hmm_setup, dim3(1), dim3(512), 0, stream,
        em, ins, flank, btm, m2e, mtm, m2i, i2m, i2i, mtd, dtm, dtd,
        lfl, lfe, e2u, e2r, e2t, P);
    hipLaunchKernelGGL(hmm_forward, dim3(128), dim3(64), 0, stream, seq, P, out);
}